// Round 12
// baseline (315.633 us; speedup 1.0000x reference)
//
#include <hip/hip_runtime.h>

#define NROWS (32*64*64)   // 131072 rows
#define D 64
#define K 512
#define EPS 0.01f          // gap band; worst-case 4-term-split score-gap error <= 8.2e-3

typedef __attribute__((ext_vector_type(8)))  short bf16x8;   // 8 bf16 in 4 VGPRs
typedef __attribute__((ext_vector_type(16))) float f32x16;   // 32x32 MFMA accumulator

__device__ __forceinline__ unsigned short f2bf(float f) {    // RTN float->bf16
    unsigned u = __float_as_uint(f);
    u += 0x7FFF + ((u >> 16) & 1);
    return (unsigned short)(u >> 16);
}
__device__ __forceinline__ float bf2f(unsigned short b) {
    return __uint_as_float(((unsigned)b) << 16);
}

// ws layout: bhi[32768 short] | blo[32768 short] | ne_d[512 double] | ne_f[512 float]
#define WS_BHI  0
#define WS_BLO  65536
#define WS_NED  131072
#define WS_NEF  135168

// Repack codebook into B-fragment order (tile t, chunk c, group g, col j -> 8 contiguous bf16),
// split hi/lo; compute |e_k|^2 fp64+fp32; zero loss slot.
__global__ void vq_prep(const float* __restrict__ emb, short* __restrict__ bhi,
                        short* __restrict__ blo, double* __restrict__ ne_d,
                        float* __restrict__ ne_f, float* __restrict__ loss_ptr) {
    int tid = blockIdx.x * 256 + threadIdx.x;
    if (tid < 4096) {   // one B-fragment (8 values) per thread
        int j = tid & 31, g = (tid >> 5) & 1, c = (tid >> 6) & 3, t = tid >> 8;
        int col = t * 32 + j, dbase = c * 16 + g * 8;
        #pragma unroll
        for (int i = 0; i < 8; ++i) {
            float v = emb[(dbase + i) * K + col];
            unsigned short h = f2bf(v);
            bhi[tid * 8 + i] = (short)h;
            blo[tid * 8 + i] = (short)f2bf(v - bf2f(h));
        }
    } else if (tid < 4096 + K) {
        int k = tid - 4096;
        double s = 0.0;
        #pragma unroll 8
        for (int d = 0; d < D; ++d) { double v = (double)emb[d * K + k]; s = fma(v, v, s); }
        ne_d[k] = s;
        ne_f[k] = (float)s;
    }
    if (tid == 0) *loss_ptr = 0.0f;
}

__global__ void __launch_bounds__(512, 4)
vq_main(const float* __restrict__ x, const float* __restrict__ emb,
        const short* __restrict__ bhi, const short* __restrict__ blo,
        const double* __restrict__ ne_d, const float* __restrict__ ne_f,
        float* __restrict__ out, float* __restrict__ loss_ptr) {
    __shared__ int   bidx_lds[256];
    __shared__ float wsum[8];

    const int tid  = threadIdx.x;
    const int wave = tid >> 6, lane = tid & 63;
    const int lo5  = lane & 31, hi = lane >> 5;
    const int rbase = blockIdx.x * 256;          // block's 256 rows
    const int row0  = rbase + wave * 32;         // wave's 32 rows

    // ---- A-fragments: x[row0+lo5][c*16+hi*8 .. +8] as bf16 hi/lo, reused across all 16 tiles ----
    bf16x8 ahi[4], alo[4];
    const float* xrow = x + (size_t)(row0 + lo5) * D;
    #pragma unroll
    for (int c = 0; c < 4; ++c) {
        const float4* p = reinterpret_cast<const float4*>(xrow + c * 16 + hi * 8);
        float4 v0 = p[0], v1 = p[1];
        float vv[8] = {v0.x, v0.y, v0.z, v0.w, v1.x, v1.y, v1.z, v1.w};
        #pragma unroll
        for (int i = 0; i < 8; ++i) {
            unsigned short h = f2bf(vv[i]);
            ahi[c][i] = (short)h;
            alo[c][i] = (short)f2bf(vv[i] - bf2f(h));
        }
    }

    // ---- stage A: per code-tile (32 codes), 16 MFMAs = full 4-term split over 4 k-chunks,
    // two independent acc chains; score = |e|^2 - 2*sim (row-constant |f|^2 drops out).
    float best[16], second[16]; int bidx[16];
    #pragma unroll
    for (int r = 0; r < 16; ++r) { best[r] = 3.4e38f; second[r] = 3.4e38f; bidx[r] = 0; }

    const bf16x8* bh8 = reinterpret_cast<const bf16x8*>(bhi);
    const bf16x8* bl8 = reinterpret_cast<const bf16x8*>(blo);

    for (int t = 0; t < 16; ++t) {
        f32x16 acc0, acc1;
        #pragma unroll
        for (int i = 0; i < 16; ++i) { acc0[i] = 0.0f; acc1[i] = 0.0f; }
        #pragma unroll
        for (int c = 0; c < 4; ++c) {
            const int F = ((t * 4 + c) * 2 + hi) * 32 + lo5;
            bf16x8 bhf = bh8[F];
            bf16x8 blf = bl8[F];
            acc0 = __builtin_amdgcn_mfma_f32_32x32x16_bf16(ahi[c], bhf, acc0, 0, 0, 0);
            acc1 = __builtin_amdgcn_mfma_f32_32x32x16_bf16(ahi[c], blf, acc1, 0, 0, 0);
            acc0 = __builtin_amdgcn_mfma_f32_32x32x16_bf16(alo[c], bhf, acc0, 0, 0, 0);
            acc1 = __builtin_amdgcn_mfma_f32_32x32x16_bf16(alo[c], blf, acc1, 0, 0, 0);
        }
        const int   kcol = t * 32 + lo5;       // this lane's code (C layout: col = lane&31)
        const float nec  = ne_f[kcol];
        #pragma unroll
        for (int r = 0; r < 16; ++r) {         // C row = (r&3) + 8*(r>>2) + 4*hi
            float s = fmaf(-2.0f, acc0[r] + acc1[r], nec);
            bool lt = s < best[r];
            second[r] = lt ? best[r] : fminf(second[r], s);
            bidx[r]   = lt ? kcol    : bidx[r];
            best[r]   = lt ? s       : best[r];
        }
    }

    // ---- merge top-2 across the 32 columns (butterfly within lane&31 group; np tie rule) ----
    #pragma unroll
    for (int off = 1; off < 32; off <<= 1) {
        #pragma unroll
        for (int r = 0; r < 16; ++r) {
            float b2 = __shfl_xor(best[r],   off);
            float s2 = __shfl_xor(second[r], off);
            int   i2 = __shfl_xor(bidx[r],   off);
            if (b2 < best[r] || (b2 == best[r] && i2 < bidx[r])) {
                second[r] = fminf(best[r], s2);
                best[r] = b2; bidx[r] = i2;
            } else {
                second[r] = fminf(second[r], b2);
            }
        }
    }

    // ---- stage B: wave-cooperative exact fp64 argmin for rows with top-2 gap < EPS ----
    unsigned fl = 0;
    #pragma unroll
    for (int r = 0; r < 16; ++r)
        if (second[r] - best[r] < EPS) fl |= (1u << r);
    unsigned fl0 = __shfl(fl, 0);    // flags of hi=0 half (lanes identical post-merge)
    unsigned fl1 = __shfl(fl, 32);   // flags of hi=1 half
    unsigned long long m = ((unsigned long long)fl1 << 16) | (unsigned long long)fl0;
    while (m) {
        int b  = __ffsll(m) - 1; m &= m - 1;
        int rh = b >> 4, rr = b & 15;
        int row = row0 + (rr & 3) + 8 * (rr >> 2) + 4 * rh;
        const float* xr = x + (size_t)row * D;
        double accd[8];
        #pragma unroll
        for (int j = 0; j < 8; ++j) accd[j] = 0.0;
        #pragma unroll 2
        for (int d = 0; d < D; ++d) {
            double fd = (double)xr[d];                       // wave-uniform
            const float* ed = emb + d * K + lane * 8;        // L2-resident, coalesced
            #pragma unroll
            for (int j = 0; j < 8; ++j)
                accd[j] = fma(fd, (double)ed[j], accd[j]);
        }
        double bv = 1e300; int bi = 0;
        #pragma unroll
        for (int j = 0; j < 8; ++j) {
            int k = lane * 8 + j;
            double dist = fma(-2.0, accd[j], ne_d[k]);       // |f|^2 dropped: same ordering
            if (dist < bv) { bv = dist; bi = k; }
        }
        #pragma unroll
        for (int off = 1; off < 64; off <<= 1) {
            double v2 = __shfl_xor(bv, off);
            int    i2 = __shfl_xor(bi, off);
            if (v2 < bv || (v2 == bv && i2 < bi)) { bv = v2; bi = i2; }
        }
        if (rh == hi) bidx[rr] = bi;
    }

    // ---- stash bidx, then coalesced qtised write + loss ----
    if (lo5 == 0) {
        #pragma unroll
        for (int r = 0; r < 16; ++r)
            bidx_lds[wave * 32 + (r & 3) + 8 * (r >> 2) + 4 * hi] = bidx[r];
    }
    __syncthreads();

    float sq = 0.0f;
    #pragma unroll
    for (int it = 0; it < 8; ++it) {
        int rlocal = wave * 32 + it * 4 + (lane >> 4);   // 4 rows per iteration, 16 lanes each
        int row = rbase + rlocal;
        int k  = bidx_lds[rlocal];
        int d0 = (lane & 15) * 4;
        float4 q;
        q.x = emb[(d0 + 0) * K + k];
        q.y = emb[(d0 + 1) * K + k];
        q.z = emb[(d0 + 2) * K + k];
        q.w = emb[(d0 + 3) * K + k];
        float4 xv = *reinterpret_cast<const float4*>(x + (size_t)row * D + d0);
        float dx = q.x - xv.x, dy = q.y - xv.y, dz = q.z - xv.z, dw = q.w - xv.w;
        sq = fmaf(dx, dx, sq); sq = fmaf(dy, dy, sq);
        sq = fmaf(dz, dz, sq); sq = fmaf(dw, dw, sq);
        *reinterpret_cast<float4*>(out + (size_t)row * D + d0) = q;   // fully coalesced
    }

    #pragma unroll
    for (int off = 32; off >= 1; off >>= 1)
        sq += __shfl_down(sq, off, 64);
    if (lane == 0) wsum[wave] = sq;
    __syncthreads();
    if (tid == 0) {
        float tot = 0.0f;
        #pragma unroll
        for (int w = 0; w < 8; ++w) tot += wsum[w];
        // loss = codebook + commit = (1 + 0.25) * mean((q - x)^2)
        atomicAdd(loss_ptr, tot * (1.25f / (float)(NROWS * D)));
    }
}

extern "C" void kernel_launch(void* const* d_in, const int* in_sizes, int n_in,
                              void* d_out, int out_size, void* d_ws, size_t ws_size,
                              hipStream_t stream) {
    const float* x   = (const float*)d_in[0];
    const float* emb = (const float*)d_in[1];
    float* out = (float*)d_out;
    float* loss_ptr = out + (out_size - 1);   // qtised flat, then loss scalar

    char* ws = (char*)d_ws;
    short*  bhi  = (short*)(ws + WS_BHI);
    short*  blo  = (short*)(ws + WS_BLO);
    double* ne_d = (double*)(ws + WS_NED);
    float*  ne_f = (float*)(ws + WS_NEF);

    vq_prep<<<18, 256, 0, stream>>>(emb, bhi, blo, ne_d, ne_f, loss_ptr);
    vq_main<<<NROWS / 256, 512, 0, stream>>>(x, emb, bhi, blo, ne_d, ne_f, out, loss_ptr);
}

// Round 15
// 189.848 us; speedup vs baseline: 1.6626x; 1.6626x over previous
//
#include <hip/hip_runtime.h>

#define NROWS (32*64*64)   // 131072 rows
#define D 64
#define K 512
#define EPS 0.01f          // gap band; 4-term-split worst-case gap error ~2.7e-3 (Cauchy-Schwarz)

typedef __attribute__((ext_vector_type(8)))  short bf16x8;   // 8 bf16 in 4 VGPRs
typedef __attribute__((ext_vector_type(16))) float f32x16;   // 32x32 MFMA accumulator

__device__ __forceinline__ unsigned short f2bf(float f) {    // RTN float->bf16
    unsigned u = __float_as_uint(f);
    u += 0x7FFF + ((u >> 16) & 1);
    return (unsigned short)(u >> 16);
}
__device__ __forceinline__ float bf2f(unsigned short b) {
    return __uint_as_float(((unsigned)b) << 16);
}

// ws layout: bhi[32768 short] | blo[32768 short] | ne_d[512 double] | ne_f[512 float]
#define WS_BHI  0
#define WS_BLO  65536
#define WS_NED  131072
#define WS_NEF  135168

// Repack codebook into B-fragment order (tile t, chunk c, group g, col j -> 8 contiguous bf16),
// split hi/lo; compute |e_k|^2 fp64+fp32; zero loss slot.
__global__ void vq_prep(const float* __restrict__ emb, short* __restrict__ bhi,
                        short* __restrict__ blo, double* __restrict__ ne_d,
                        float* __restrict__ ne_f, float* __restrict__ loss_ptr) {
    int tid = blockIdx.x * 256 + threadIdx.x;
    if (tid < 4096) {   // one B-fragment (8 values) per thread
        int j = tid & 31, g = (tid >> 5) & 1, c = (tid >> 6) & 3, t = tid >> 8;
        int col = t * 32 + j, dbase = c * 16 + g * 8;
        #pragma unroll
        for (int i = 0; i < 8; ++i) {
            float v = emb[(dbase + i) * K + col];
            unsigned short h = f2bf(v);
            bhi[tid * 8 + i] = (short)h;
            blo[tid * 8 + i] = (short)f2bf(v - bf2f(h));
        }
    } else if (tid < 4096 + K) {
        int k = tid - 4096;
        double s = 0.0;
        #pragma unroll 8
        for (int d = 0; d < D; ++d) { double v = (double)emb[d * K + k]; s = fma(v, v, s); }
        ne_d[k] = s;
        ne_f[k] = (float)s;
    }
    if (tid == 0) *loss_ptr = 0.0f;
}

__global__ void __launch_bounds__(512)
vq_main(const float* __restrict__ x, const float* __restrict__ emb,
        const short* __restrict__ bhi, const short* __restrict__ blo,
        const double* __restrict__ ne_d, const float* __restrict__ ne_f,
        float* __restrict__ out, float* __restrict__ loss_ptr) {
    __shared__ int   bidx_lds[256];
    __shared__ float wsum[8];

    const int tid  = threadIdx.x;
    const int wave = tid >> 6, lane = tid & 63;
    const int lo5  = lane & 31, hi = lane >> 5;
    const int rbase = blockIdx.x * 256;          // block's 256 rows
    const int row0  = rbase + wave * 32;         // wave's 32 rows

    // ---- A-fragments: x[row0+lo5][c*16+hi*8 .. +8] as bf16 hi/lo, reused across all 16 tiles ----
    bf16x8 ahi[4], alo[4];
    const float* xrow = x + (size_t)(row0 + lo5) * D;
    #pragma unroll
    for (int c = 0; c < 4; ++c) {
        const float4* p = reinterpret_cast<const float4*>(xrow + c * 16 + hi * 8);
        float4 v0 = p[0], v1 = p[1];
        float vv[8] = {v0.x, v0.y, v0.z, v0.w, v1.x, v1.y, v1.z, v1.w};
        #pragma unroll
        for (int i = 0; i < 8; ++i) {
            unsigned short h = f2bf(vv[i]);
            ahi[c][i] = (short)h;
            alo[c][i] = (short)f2bf(vv[i] - bf2f(h));
        }
    }

    // ---- stage A: per code-tile (32 codes), 16 MFMAs = full 4-term split over 4 k-chunks,
    // single accumulator (round-11 register structure; no spill).
    // score = |e|^2 - 2*sim  (row-constant |f|^2 drops out of argmin), per-lane top-2.
    float best[16], second[16]; int bidx[16];
    #pragma unroll
    for (int r = 0; r < 16; ++r) { best[r] = 3.4e38f; second[r] = 3.4e38f; bidx[r] = 0; }

    const bf16x8* bh8 = reinterpret_cast<const bf16x8*>(bhi);
    const bf16x8* bl8 = reinterpret_cast<const bf16x8*>(blo);

    for (int t = 0; t < 16; ++t) {
        f32x16 acc;
        #pragma unroll
        for (int i = 0; i < 16; ++i) acc[i] = 0.0f;
        #pragma unroll
        for (int c = 0; c < 4; ++c) {
            const int F = ((t * 4 + c) * 2 + hi) * 32 + lo5;
            bf16x8 bhf = bh8[F];
            bf16x8 blf = bl8[F];
            acc = __builtin_amdgcn_mfma_f32_32x32x16_bf16(ahi[c], bhf, acc, 0, 0, 0);
            acc = __builtin_amdgcn_mfma_f32_32x32x16_bf16(ahi[c], blf, acc, 0, 0, 0);
            acc = __builtin_amdgcn_mfma_f32_32x32x16_bf16(alo[c], bhf, acc, 0, 0, 0);
            acc = __builtin_amdgcn_mfma_f32_32x32x16_bf16(alo[c], blf, acc, 0, 0, 0);
        }
        const int   kcol = t * 32 + lo5;       // this lane's code (C layout: col = lane&31)
        const float nec  = ne_f[kcol];
        #pragma unroll
        for (int r = 0; r < 16; ++r) {         // C row = (r&3) + 8*(r>>2) + 4*hi
            float s = fmaf(-2.0f, acc[r], nec);
            bool lt = s < best[r];
            second[r] = lt ? best[r] : fminf(second[r], s);
            bidx[r]   = lt ? kcol    : bidx[r];
            best[r]   = lt ? s       : best[r];
        }
    }

    // ---- merge top-2 across the 32 columns (butterfly within lane&31 group; np tie rule) ----
    #pragma unroll
    for (int off = 1; off < 32; off <<= 1) {
        #pragma unroll
        for (int r = 0; r < 16; ++r) {
            float b2 = __shfl_xor(best[r],   off);
            float s2 = __shfl_xor(second[r], off);
            int   i2 = __shfl_xor(bidx[r],   off);
            if (b2 < best[r] || (b2 == best[r] && i2 < bidx[r])) {
                second[r] = fminf(best[r], s2);
                best[r] = b2; bidx[r] = i2;
            } else {
                second[r] = fminf(second[r], b2);
            }
        }
    }

    // ---- stage B: wave-cooperative exact fp64 argmin for rows with top-2 gap < EPS ----
    unsigned fl = 0;
    #pragma unroll
    for (int r = 0; r < 16; ++r)
        if (second[r] - best[r] < EPS) fl |= (1u << r);
    unsigned fl0 = __shfl(fl, 0);    // flags of hi=0 half (lanes identical post-merge)
    unsigned fl1 = __shfl(fl, 32);   // flags of hi=1 half
    unsigned long long m = ((unsigned long long)fl1 << 16) | (unsigned long long)fl0;
    while (m) {
        int b  = __ffsll(m) - 1; m &= m - 1;
        int rh = b >> 4, rr = b & 15;
        int row = row0 + (rr & 3) + 8 * (rr >> 2) + 4 * rh;
        const float* xr = x + (size_t)row * D;
        double accd[8];
        #pragma unroll
        for (int j = 0; j < 8; ++j) accd[j] = 0.0;
        #pragma unroll 4
        for (int d = 0; d < D; ++d) {
            double fd = (double)xr[d];                       // wave-uniform
            const float* ed = emb + d * K + lane * 8;        // L2-resident, coalesced
            #pragma unroll
            for (int j = 0; j < 8; ++j)
                accd[j] = fma(fd, (double)ed[j], accd[j]);
        }
        double bv = 1e300; int bi = 0;
        #pragma unroll
        for (int j = 0; j < 8; ++j) {
            int k = lane * 8 + j;
            double dist = fma(-2.0, accd[j], ne_d[k]);       // |f|^2 dropped: same ordering
            if (dist < bv) { bv = dist; bi = k; }
        }
        #pragma unroll
        for (int off = 1; off < 64; off <<= 1) {
            double v2 = __shfl_xor(bv, off);
            int    i2 = __shfl_xor(bi, off);
            if (v2 < bv || (v2 == bv && i2 < bi)) { bv = v2; bi = i2; }
        }
        if (rh == hi) bidx[rr] = bi;
    }

    // ---- stash bidx, then coalesced qtised write + loss ----
    if (lo5 == 0) {
        #pragma unroll
        for (int r = 0; r < 16; ++r)
            bidx_lds[wave * 32 + (r & 3) + 8 * (r >> 2) + 4 * hi] = bidx[r];
    }
    __syncthreads();

    float sq = 0.0f;
    #pragma unroll
    for (int it = 0; it < 8; ++it) {
        int rlocal = wave * 32 + it * 4 + (lane >> 4);   // 4 rows per iteration, 16 lanes each
        int row = rbase + rlocal;
        int k  = bidx_lds[rlocal];
        int d0 = (lane & 15) * 4;
        float4 q;
        q.x = emb[(d0 + 0) * K + k];
        q.y = emb[(d0 + 1) * K + k];
        q.z = emb[(d0 + 2) * K + k];
        q.w = emb[(d0 + 3) * K + k];
        float4 xv = *reinterpret_cast<const float4*>(x + (size_t)row * D + d0);
        float dx = q.x - xv.x, dy = q.y - xv.y, dz = q.z - xv.z, dw = q.w - xv.w;
        sq = fmaf(dx, dx, sq); sq = fmaf(dy, dy, sq);
        sq = fmaf(dz, dz, sq); sq = fmaf(dw, dw, sq);
        *reinterpret_cast<float4*>(out + (size_t)row * D + d0) = q;   // fully coalesced
    }

    #pragma unroll
    for (int off = 32; off >= 1; off >>= 1)
        sq += __shfl_down(sq, off, 64);
    if (lane == 0) wsum[wave] = sq;
    __syncthreads();
    if (tid == 0) {
        float tot = 0.0f;
        #pragma unroll
        for (int w = 0; w < 8; ++w) tot += wsum[w];
        // loss = codebook + commit = (1 + 0.25) * mean((q - x)^2)
        atomicAdd(loss_ptr, tot * (1.25f / (float)(NROWS * D)));
    }
}

extern "C" void kernel_launch(void* const* d_in, const int* in_sizes, int n_in,
                              void* d_out, int out_size, void* d_ws, size_t ws_size,
                              hipStream_t stream) {
    const float* x   = (const float*)d_in[0];
    const float* emb = (const float*)d_in[1];
    float* out = (float*)d_out;
    float* loss_ptr = out + (out_size - 1);   // qtised flat, then loss scalar

    char* ws = (char*)d_ws;
    short*  bhi  = (short*)(ws + WS_BHI);
    short*  blo  = (short*)(ws + WS_BLO);
    double* ne_d = (double*)(ws + WS_NED);
    float*  ne_f = (float*)(ws + WS_NEF);

    vq_prep<<<18, 256, 0, stream>>>(emb, bhi, blo, ne_d, ne_f, loss_ptr);
    vq_main<<<NROWS / 256, 512, 0, stream>>>(x, emb, bhi, blo, ne_d, ne_f, out, loss_ptr);
}